// Round 11
// baseline (24.247 us; speedup 1.0000x reference)
//
#include <hip/hip_runtime.h>

#define K_TOTAL 32768
#define R_TOTAL 128
#define A_DIM   16
#define NBUCK   32
#define RHO_STR 20   // rho row padded to 20 floats (80 B, 16B-aligned)

// d_ws layout (bytes):
//   [0,     8192)   lut    uint4[A_DIM*NBUCK=512]  bit r => rule r candidate
//   [8192,  40960)  rules4 float4[R_TOTAL*A_DIM] = {A, 1/(B-A), D, 1/(D-C)}
//   [40960, 51200)  rhop   float[R_TOTAL*RHO_STR] (col 16 = bias)

// ---------------------------------------------------------------------------
// Kernel 1: ONE block, 1024 threads. Fold sort+rcp constants (amin/dmax are
// free byproducts of the sort -> LDS), copy rho padded, then 512 threads
// build the 512-entry LUT from LDS (wave-uniform broadcast reads: lanes
// 0-31 share dim a -> same address).
// ---------------------------------------------------------------------------
__global__ __launch_bounds__(1024)
void build_tables(const float* __restrict__ abcd, const float* __restrict__ rho,
                  uint4* __restrict__ lut, float4* __restrict__ rules4,
                  float* __restrict__ rhop) {
    __shared__ float2 mnmx[R_TOTAL * A_DIM];   // 16 KB: {amin, dmax} per (r,a)
    const int t = threadIdx.x;

    #pragma unroll
    for (int i = 0; i < 2; ++i) {
        int e = t + i * 1024;                  // (r,a), < 2048
        float4 v = ((const float4*)abcd)[e];
        float v0 = v.x, v1 = v.y, v2 = v.z, v3 = v.w, s;
        s = fminf(v0, v1); v1 = fmaxf(v0, v1); v0 = s;
        s = fminf(v2, v3); v3 = fmaxf(v2, v3); v2 = s;
        s = fminf(v0, v2); v2 = fmaxf(v0, v2); v0 = s;
        s = fminf(v1, v3); v3 = fmaxf(v1, v3); v1 = s;
        s = fminf(v1, v2); v2 = fmaxf(v1, v2); v1 = s;
        // v0<=v1<=v2<=v3
        rules4[e] = make_float4(v0, __builtin_amdgcn_rcpf(v1 - v0),
                                v3, __builtin_amdgcn_rcpf(v3 - v2));
        mnmx[e] = make_float2(v0, v3);
    }
    #pragma unroll
    for (int i = 0; i < 3; ++i) {
        int f = t + i * 1024;                  // rho element, < 2176
        if (f < R_TOTAL * (A_DIM + 1)) {
            int r = f / (A_DIM + 1);
            int c = f - r * (A_DIM + 1);
            rhop[r * RHO_STR + c] = rho[f];    // c==16 -> bias
        }
    }
    __syncthreads();

    if (t < A_DIM * NBUCK) {                   // 512 LUT entries
        int a = t >> 5;                        // dim
        int b = t & (NBUCK - 1);               // bucket
        float lo = (float)(b - 1) * 0.03125f;  // widened -1 bucket (exact fp)
        float hi = (float)(b + 2) * 0.03125f;  // widened +1 bucket
        unsigned m0 = 0, m1 = 0, m2 = 0, m3 = 0;
        #pragma unroll 4
        for (int r = 0; r < 32; ++r) {         // 4 rule-words per iter, static
            float2 c0 = mnmx[((r      ) << 4) + a];
            float2 c1 = mnmx[((r +  32) << 4) + a];
            float2 c2 = mnmx[((r +  64) << 4) + a];
            float2 c3 = mnmx[((r +  96) << 4) + a];
            unsigned bit = 1u << r;
            if (c0.x <= hi && c0.y >= lo) m0 |= bit;
            if (c1.x <= hi && c1.y >= lo) m1 |= bit;
            if (c2.x <= hi && c2.y >= lo) m2 |= bit;
            if (c3.x <= hi && c3.y >= lo) m3 |= bit;
        }
        lut[t] = make_uint4(m0, m1, m2, m3);
    }
}

// ---------------------------------------------------------------------------
// Kernel 2: sparse main. 256 blocks x 128 threads; thread = one k.
// 16 LUT gathers direct from L2 (no LDS staging), AND -> ~0.17 candidate
// rules per k, exact membership+z only for candidates (false positives
// multiply out to exact 0 -> bitwise-equal support to reference).
// ---------------------------------------------------------------------------
__global__ __launch_bounds__(128)
void fuzzy_sparse(const float* __restrict__ input,
                  const uint4* __restrict__ lut,
                  const float4* __restrict__ rules4,
                  const float* __restrict__ rhop,
                  float* __restrict__ out) {
    const int k = blockIdx.x * 128 + threadIdx.x;

    float x[A_DIM];
    {
        const float4* xp = (const float4*)(input + (size_t)k * A_DIM);
        float4 a0 = xp[0], a1 = xp[1], a2 = xp[2], a3 = xp[3];
        x[0]=a0.x;  x[1]=a0.y;  x[2]=a0.z;  x[3]=a0.w;
        x[4]=a1.x;  x[5]=a1.y;  x[6]=a1.z;  x[7]=a1.w;
        x[8]=a2.x;  x[9]=a2.y;  x[10]=a2.z; x[11]=a2.w;
        x[12]=a3.x; x[13]=a3.y; x[14]=a3.z; x[15]=a3.w;
    }

    // AND the 16 per-dim candidate masks (independent L2 gathers)
    uint4 mm;
    {
        int b0 = min(NBUCK - 1, (int)(x[0] * (float)NBUCK));
        mm = lut[b0];
        #pragma unroll
        for (int a = 1; a < A_DIM; ++a) {
            int b = min(NBUCK - 1, (int)(x[a] * (float)NBUCK));
            uint4 v = lut[a * NBUCK + b];
            mm.x &= v.x; mm.y &= v.y; mm.z &= v.z; mm.w &= v.w;
        }
    }

    unsigned long long mlo = ((unsigned long long)mm.y << 32) | mm.x;
    unsigned long long mhi = ((unsigned long long)mm.w << 32) | mm.z;

    float num = 0.0f, den = 0.0f;
    while (mlo | mhi) {
        int r;
        if (mlo) { r = __builtin_ctzll(mlo);      mlo &= mlo - 1; }
        else     { r = 64 + __builtin_ctzll(mhi); mhi &= mhi - 1; }

        const float4* __restrict__ rp = rules4 + (r << 4);
        float w = 1.0f;
        #pragma unroll
        for (int a = 0; a < A_DIM; ++a) {
            float4 c   = rp[a];
            float rise = (x[a] - c.x) * c.y;
            float fall = (c.z - x[a]) * c.w;
            w *= __builtin_amdgcn_fmed3f(fminf(rise, fall), 0.0f, 1.0f);
        }
        if (w != 0.0f) {
            const float* __restrict__ rh = rhop + r * RHO_STR;
            float z = rh[A_DIM];
            #pragma unroll
            for (int a = 0; a < A_DIM; ++a) z = fmaf(x[a], rh[a], z);
            num = fmaf(z, w, num);
            den += w;
        }
    }

    out[k] = num * __builtin_amdgcn_rcpf(den + 1e-13f);
}

// ---------------------------------------------------------------------------
extern "C" void kernel_launch(void* const* d_in, const int* in_sizes, int n_in,
                              void* d_out, int out_size, void* d_ws, size_t ws_size,
                              hipStream_t stream) {
    const float* input = (const float*)d_in[0];   // (K, A)    fp32
    const float* abcd  = (const float*)d_in[1];   // (R, A, 4) fp32
    const float* rho   = (const float*)d_in[2];   // (R, A+1)  fp32
    float* out = (float*)d_out;                   // (K,)      fp32

    char* ws = (char*)d_ws;
    uint4*  lut    = (uint4*)(ws);                // 8 KB
    float4* rules4 = (float4*)(ws + 8192);        // 32 KB
    float*  rhop   = (float*)(ws + 40960);        // 10 KB

    build_tables<<<1, 1024, 0, stream>>>(abcd, rho, lut, rules4, rhop);
    fuzzy_sparse<<<K_TOTAL / 128, 128, 0, stream>>>(input, lut, rules4, rhop, out);
}

// Round 12
// 12.663 us; speedup vs baseline: 1.9147x; 1.9147x over previous
//
#include <hip/hip_runtime.h>

#define K_TOTAL 32768
#define R_TOTAL 128
#define A_DIM   16
#define KB      128      // k-points per block (2 per lane)
#define RPW     8        // rules per wave (16 waves x 8 = 128)

#define REC 84   // floats per rule record in LDS (336 B = 21*16 -> f4-aligned)
// per-rule LDS record layout (floats), pair p = dims {2p, 2p+1}:
//   [ 4p .. 4p+3 ]      Q0[p] = { IBA0, IBA1, C1_0, C1_1 }   (p = 0..7)
//   [32+4p .. 32+4p+3]  Q1[p] = { NID0, NID1, C3_0, C3_1 }
//   [64..79]            rho[0..15]
//   [80]                bias ; [81..83] pad

typedef float v2f __attribute__((ext_vector_type(2)));

__device__ __forceinline__ float clamp01(float v) {
    return __builtin_amdgcn_fmed3f(v, 0.0f, 1.0f);
}

// one dim-pair, two k-instances; 2x ds_read_b128 delivers all 8 constants
__device__ __forceinline__ void memb_pair2(const float* rec, int p,
                                           const v2f* Xa, const v2f* Xb,
                                           v2f& Wa, v2f& Wb) {
    float4 q0 = *(const float4*)(rec + 4 * p);        // ds_read_b128
    float4 q1 = *(const float4*)(rec + 32 + 4 * p);   // ds_read_b128
    v2f iba = (v2f){q0.x, q0.y}, c1 = (v2f){q0.z, q0.w};
    v2f nid = (v2f){q1.x, q1.y}, c3 = (v2f){q1.z, q1.w};
    v2f ra = Xa[p] * iba + c1;    // v_pk_fma_f32
    v2f fa = Xa[p] * nid + c3;
    v2f rb = Xb[p] * iba + c1;
    v2f fb = Xb[p] * nid + c3;
    v2f Ma, Mb;
    Ma.x = clamp01(fminf(ra.x, fa.x));
    Ma.y = clamp01(fminf(ra.y, fa.y));
    Mb.x = clamp01(fminf(rb.x, fb.x));
    Mb.y = clamp01(fminf(rb.y, fb.y));
    Wa *= Ma;
    Wb *= Mb;
}

// Single fused kernel. 256 blocks x 1024 threads (16 waves, 1 block/CU).
// Block owns 128 k's: lane carries k = kbase+lane and kbase+64+lane.
// Wave wv folds ONLY its own 8 rules into its own LDS region (2 KB
// contiguous global reads), then proceeds with a wave-local lgkmcnt fence
// -- no block barrier between fold and compute. Phase 2: wave-uniform
// b128 LDS broadcasts feed packed-fp32 VALU for both k-instances;
// early-outs after dims 8/12/16 skip work whose contribution is exact +0.
__global__ __launch_bounds__(1024, 4)
void fuzzy_fused(const float* __restrict__ input,
                 const float* __restrict__ abcd,
                 const float* __restrict__ rho,
                 float* __restrict__ out) {
    __shared__ __align__(16) float tab[R_TOTAL * REC];   // 43008 B
    __shared__ float nsh[16][KB];                        // 8192 B
    __shared__ float dsh[16][KB];                        // 8192 B

    const int t     = threadIdx.x;
    const int lane  = t & 63;
    const int wv    = __builtin_amdgcn_readfirstlane(t >> 6);
    const int kbase = blockIdx.x * KB;
    float* wtab = tab + wv * RPW * REC;

    // -------- per-wave fold: 8 rules x 16 dims = 128 entries, 2/lane -------
    #pragma unroll
    for (int i = 0; i < 2; ++i) {
        int e  = lane + 64 * i;                // 0..127 within this wave
        int rr = e >> 4, a = e & 15, p = a >> 1, sl = a & 1;
        float4 v = ((const float4*)abcd)[wv * 128 + e];
        float v0 = v.x, v1 = v.y, v2 = v.z, v3 = v.w, s;
        s = fminf(v0, v1); v1 = fmaxf(v0, v1); v0 = s;
        s = fminf(v2, v3); v3 = fmaxf(v2, v3); v2 = s;
        s = fminf(v0, v2); v2 = fmaxf(v0, v2); v0 = s;
        s = fminf(v1, v3); v3 = fmaxf(v1, v3); v1 = s;
        s = fminf(v1, v2); v2 = fmaxf(v1, v2); v1 = s;
        // v0<=v1<=v2<=v3
        float iba = __builtin_amdgcn_rcpf(v1 - v0);
        float idc = __builtin_amdgcn_rcpf(v3 - v2);
        float* q = wtab + rr * REC;
        q[4 * p + sl]          =  iba;
        q[4 * p + 2 + sl]      = -v0 * iba;
        q[32 + 4 * p + sl]     = -idc;
        q[32 + 4 * p + 2 + sl] =  v3 * idc;
    }
    // rho for this wave's 8 rules: 8*17 = 136 floats, contiguous in global
    #pragma unroll
    for (int i = 0; i < 3; ++i) {
        int f = lane + 64 * i;
        if (f < RPW * (A_DIM + 1)) {
            int rr = f / (A_DIM + 1);
            int c  = f - rr * (A_DIM + 1);
            wtab[rr * REC + 64 + c] = rho[wv * RPW * (A_DIM + 1) + f];
        }
    }

    // per-lane coordinates for the two k-instances (overlap fold latency)
    v2f Xa[8], Xb[8];
    {
        const float4* xp = (const float4*)(input + (size_t)(kbase + lane) * A_DIM);
        float4 a0 = xp[0], a1 = xp[1], a2 = xp[2], a3 = xp[3];
        Xa[0] = (v2f){a0.x, a0.y}; Xa[1] = (v2f){a0.z, a0.w};
        Xa[2] = (v2f){a1.x, a1.y}; Xa[3] = (v2f){a1.z, a1.w};
        Xa[4] = (v2f){a2.x, a2.y}; Xa[5] = (v2f){a2.z, a2.w};
        Xa[6] = (v2f){a3.x, a3.y}; Xa[7] = (v2f){a3.z, a3.w};
        const float4* yp = (const float4*)(input + (size_t)(kbase + 64 + lane) * A_DIM);
        float4 b0 = yp[0], b1 = yp[1], b2 = yp[2], b3 = yp[3];
        Xb[0] = (v2f){b0.x, b0.y}; Xb[1] = (v2f){b0.z, b0.w};
        Xb[2] = (v2f){b1.x, b1.y}; Xb[3] = (v2f){b1.z, b1.w};
        Xb[4] = (v2f){b2.x, b2.y}; Xb[5] = (v2f){b2.z, b2.w};
        Xb[6] = (v2f){b3.x, b3.y}; Xb[7] = (v2f){b3.z, b3.w};
    }

    // wave-local fence: this wave's LDS writes complete before its reads.
    // (No cross-wave hazard: each wave reads only its own region.)
    asm volatile("s_waitcnt lgkmcnt(0)" ::: "memory");
    __builtin_amdgcn_sched_barrier(0);

    // -------- Phase 2: stream this wave's 8 rules --------------------------
    float numA = 0.0f, denA = 0.0f, numB = 0.0f, denB = 0.0f;

    #pragma unroll
    for (int rr = 0; rr < RPW; ++rr) {
        const float* rec = wtab + rr * REC;    // wave-uniform -> broadcasts

        v2f Wa = (v2f){1.0f, 1.0f}, Wb = (v2f){1.0f, 1.0f};
        memb_pair2(rec, 0, Xa, Xb, Wa, Wb);
        memb_pair2(rec, 1, Xa, Xb, Wa, Wb);
        memb_pair2(rec, 2, Xa, Xb, Wa, Wb);
        memb_pair2(rec, 3, Xa, Xb, Wa, Wb);
        float w8a = Wa.x * Wa.y, w8b = Wb.x * Wb.y;
        if (__any((w8a != 0.0f) | (w8b != 0.0f))) {          // skip p~0.11
            memb_pair2(rec, 4, Xa, Xb, Wa, Wb);
            memb_pair2(rec, 5, Xa, Xb, Wa, Wb);
            float w12a = Wa.x * Wa.y, w12b = Wb.x * Wb.y;
            if (__any((w12a != 0.0f) | (w12b != 0.0f))) {    // skip p~0.75
                memb_pair2(rec, 6, Xa, Xb, Wa, Wb);
                memb_pair2(rec, 7, Xa, Xb, Wa, Wb);
                float wfa = Wa.x * Wa.y, wfb = Wb.x * Wb.y;
                if (__any((wfa != 0.0f) | (wfb != 0.0f))) {  // skip p~0.96
                    v2f accA = (v2f){rec[80], 0.0f};         // bias
                    v2f accB = (v2f){rec[80], 0.0f};
                    #pragma unroll
                    for (int p4 = 0; p4 < 4; ++p4) {
                        float4 rh = *(const float4*)(rec + 64 + 4 * p4);
                        v2f r0 = (v2f){rh.x, rh.y}, r1 = (v2f){rh.z, rh.w};
                        accA += Xa[2*p4] * r0;  accA += Xa[2*p4+1] * r1;
                        accB += Xb[2*p4] * r0;  accB += Xb[2*p4+1] * r1;
                    }
                    float za = accA.x + accA.y;
                    float zb = accB.x + accB.y;
                    numA = fmaf(za, wfa, numA);  denA += wfa;
                    numB = fmaf(zb, wfb, numB);  denB += wfb;
                }
            }
        }
    }

    // -------- Phase 3: reduce across the 16 waves --------------------------
    nsh[wv][lane]      = numA;
    dsh[wv][lane]      = denA;
    nsh[wv][64 + lane] = numB;
    dsh[wv][64 + lane] = denB;
    __syncthreads();

    if (t < KB) {
        float n = 0.0f, d = 0.0f;
        #pragma unroll
        for (int c = 0; c < 16; ++c) { n += nsh[c][t]; d += dsh[c][t]; }
        out[kbase + t] = n * __builtin_amdgcn_rcpf(d + 1e-13f);
    }
}

// ---------------------------------------------------------------------------
extern "C" void kernel_launch(void* const* d_in, const int* in_sizes, int n_in,
                              void* d_out, int out_size, void* d_ws, size_t ws_size,
                              hipStream_t stream) {
    const float* input = (const float*)d_in[0];   // (K, A)    fp32
    const float* abcd  = (const float*)d_in[1];   // (R, A, 4) fp32
    const float* rho   = (const float*)d_in[2];   // (R, A+1)  fp32
    float* out = (float*)d_out;                   // (K,)      fp32

    fuzzy_fused<<<K_TOTAL / KB, 1024, 0, stream>>>(input, abcd, rho, out);
}